// Round 1
// baseline (63.340 us; speedup 1.0000x reference)
//
#include <hip/hip_runtime.h>
#include <stdint.h>

// out[b,o,p] = sum_{r,c} mat0[b,c,p] * mat1[o,c,r]*Alpha[r] * mask[r,p]
// Single GEMM: M=256 (o), N=32768 (n=b*4096+p), K=2048 (k=c*8+r).
// A[o,k] = mat1[o,c,r]*Alpha[r]  (prepped bf16 in d_ws, layout [c][o][r] = [k>>3][o][k&7])
// B[k,n] = mat0[b,c,p]*mask[r,p] (generated on the staging path, bf16)

typedef __attribute__((ext_vector_type(8))) short short8;
typedef __attribute__((ext_vector_type(4))) float f32x4;

#define C_IN  256
#define HW_   4096
#define O_DIM 256
#define BM    128
#define BN    128
#define NRND  64   // K rounds = 2048/32

__device__ __forceinline__ short f2bf(float x) {
  uint32_t u = __float_as_uint(x);
  u += 0x7FFFu + ((u >> 16) & 1u);   // round-to-nearest-even
  return (short)(u >> 16);
}

__global__ __launch_bounds__(256) void prep_w_kernel(
    const float* __restrict__ mat1, const float* __restrict__ Alpha,
    const int* __restrict__ use_alpha, short* __restrict__ Aprep) {
  int t = blockIdx.x * 256 + threadIdx.x;   // 65536 threads: o = t&255, c = t>>8
  int o = t & 255;
  int c = t >> 8;
  int ua = use_alpha[0];
  const float* src = mat1 + ((size_t)o * C_IN + c) * 8;
  short8 v;
#pragma unroll
  for (int r = 0; r < 8; ++r) {
    float s = ua ? Alpha[r] : 1.0f;
    v[r] = f2bf(src[r] * s);
  }
  // layout: slot (c*256 + o), 8 bf16 (r fastest) -> 16B coalesced along o
  *(short8*)(Aprep + ((size_t)c * 256 + o) * 8) = v;
}

__global__ __launch_bounds__(256, 2) void gemm_deform_kernel(
    const float* __restrict__ mat0, const short* __restrict__ Aprep,
    const float* __restrict__ mask, float* __restrict__ out) {
  // LDS: [kp][row/n][8 bf16] slots of 16B; slot = kp*128 + idx
  __shared__ short8 A_lds[512];   // 8 KiB
  __shared__ short8 B_lds[512];   // 8 KiB

  int bid = blockIdx.x;
  int wg = (bid & 7) * 64 + (bid >> 3);   // XCD swizzle, 512 % 8 == 0 -> bijective
  int tile_m = wg & 1;                     // M fastest: pair shares mat0 tile in L2
  int tile_n = wg >> 1;                    // 0..255
  int o0 = tile_m * BM;
  int n0 = tile_n * BN;
  int b  = n0 >> 12;
  int p0 = n0 & 4095;

  int t    = threadIdx.x;
  int lane = t & 63;
  int w    = t >> 6;        // wave id 0..3
  int wr   = w >> 1, wc = w & 1;

  // B staging assignment: thread t owns LDS slots t and t+256
  int ns = t & 127;         // n within tile
  int cr = t >> 7;          // c offset 0/1 (and cr+2 for second slot)

  const float* m0 = mat0 + (size_t)b * C_IN * HW_ + p0;

  // per-thread mask registers: mk[r] = mask[r, p0+ns] (constant over K loop)
  float mk[8];
#pragma unroll
  for (int r = 0; r < 8; ++r) mk[r] = mask[(size_t)r * HW_ + p0 + ns];

  f32x4 zero4 = {0.f, 0.f, 0.f, 0.f};
  f32x4 acc[4][4];
#pragma unroll
  for (int mi = 0; mi < 4; ++mi)
#pragma unroll
    for (int ni = 0; ni < 4; ++ni) acc[mi][ni] = zero4;

  const __attribute__((address_space(1))) uint32_t* gA =
      (const __attribute__((address_space(1))) uint32_t*)Aprep;
  __attribute__((address_space(3))) uint32_t* lA =
      (__attribute__((address_space(3))) uint32_t*)A_lds;

  int kp = lane >> 4;
  int li = lane & 15;

  for (int rd = 0; rd < NRND; ++rd) {
    int c0 = rd * 4;   // 4 c-rows per round; k = (c0+kp)*8 + r

    // ---- stage A: wave w fills kp=w plane via global_load_lds (16B/lane) ----
    {
      int gslot = (c0 + w) * 256 + o0 + lane;            // Aprep slot (16B units)
      __builtin_amdgcn_global_load_lds(gA + (size_t)gslot * 4,
                                       lA + (size_t)(w * 128) * 4, 16, 0, 0);
      __builtin_amdgcn_global_load_lds(gA + (size_t)(gslot + 64) * 4,
                                       lA + (size_t)(w * 128 + 64) * 4, 16, 0, 0);
    }

    // ---- stage B: generate Beff = mat0 * mask, cvt bf16, 2x ds_write_b128 ----
    {
      float fA = m0[(size_t)(c0 + cr) * HW_ + ns];
      float fB = m0[(size_t)(c0 + cr + 2) * HW_ + ns];
      short8 pa, pb;
#pragma unroll
      for (int r = 0; r < 8; ++r) {
        pa[r] = f2bf(fA * mk[r]);
        pb[r] = f2bf(fB * mk[r]);
      }
      B_lds[t]       = pa;   // slot = cr*128 + ns
      B_lds[t + 256] = pb;   // slot = (cr+2)*128 + ns
    }

    __syncthreads();   // drains vmcnt (global_load_lds) + lgkmcnt (ds_write)

    // ---- compute: 8 ds_read_b128 + 16 MFMA per wave ----
    short8 af[4], bf[4];
#pragma unroll
    for (int mi = 0; mi < 4; ++mi)
      af[mi] = A_lds[kp * 128 + wr * 64 + mi * 16 + li];
#pragma unroll
    for (int ni = 0; ni < 4; ++ni)
      bf[ni] = B_lds[kp * 128 + wc * 64 + ni * 16 + li];
#pragma unroll
    for (int mi = 0; mi < 4; ++mi)
#pragma unroll
      for (int ni = 0; ni < 4; ++ni)
        acc[mi][ni] = __builtin_amdgcn_mfma_f32_16x16x32_bf16(
            af[mi], bf[ni], acc[mi][ni], 0, 0, 0);

    __syncthreads();   // protect LDS from next round's staging
  }

  // ---- epilogue: C/D layout col=lane&15, row=(lane>>4)*4+j ----
  size_t obase = (size_t)b * O_DIM * HW_ + p0;
#pragma unroll
  for (int mi = 0; mi < 4; ++mi) {
#pragma unroll
    for (int ni = 0; ni < 4; ++ni) {
      int col = wc * 64 + ni * 16 + li;
#pragma unroll
      for (int j = 0; j < 4; ++j) {
        int row = o0 + wr * 64 + mi * 16 + (lane >> 4) * 4 + j;
        out[obase + (size_t)row * HW_ + col] = acc[mi][ni][j];
      }
    }
  }
}

extern "C" void kernel_launch(void* const* d_in, const int* in_sizes, int n_in,
                              void* d_out, int out_size, void* d_ws, size_t ws_size,
                              hipStream_t stream) {
  const float* mat0     = (const float*)d_in[0];   // [8,256,64,64]
  const float* mat1     = (const float*)d_in[1];   // [256,256,8]
  const float* mask     = (const float*)d_in[2];   // [8,64,64]
  const float* Alpha    = (const float*)d_in[3];   // [8]
  const int*   use_alpha= (const int*)d_in[4];     // [1]
  (void)in_sizes; (void)n_in; (void)out_size; (void)ws_size;

  short* Aprep = (short*)d_ws;                     // 256*2048*2B = 1 MiB scratch
  float* outp  = (float*)d_out;

  prep_w_kernel<<<256, 256, 0, stream>>>(mat1, Alpha, use_alpha, Aprep);
  gemm_deform_kernel<<<512, 256, 0, stream>>>(mat0, Aprep, mask, outp);
}

// Round 2
// 61.934 us; speedup vs baseline: 1.0227x; 1.0227x over previous
//
#include <hip/hip_runtime.h>
#include <hip/hip_bf16.h>
#include <stdint.h>

// out[b,o,p] = sum_{r,c} mat0[b,c,p] * mat1[o,c,r]*Alpha[r] * mask[r,p]
// Single GEMM: M=256 (o), N=32768 (n=b*4096+p), K=2048 (k=c*8+r).
// A[o,k] = mat1[o,c,r]*Alpha[r]  (prepped bf16 in d_ws, layout [c][o][r])
// B[k,n] = mat0[b,c,p]*mask[r,p] (generated on the staging path, bf16)
// Round 2: double-buffered 2-phase pipeline (issue-early/write-late), BK=64.

typedef __attribute__((ext_vector_type(8))) short short8;
typedef __attribute__((ext_vector_type(4))) float f32x4;

#define C_IN  256
#define HW_   4096
#define O_DIM 256
#define BM    128
#define BN    128
#define BKC   8     // c-planes per round (K-step = 64)
#define NRND  32    // 256 / 8

__device__ __forceinline__ short f2bf(float x) {
  union { __hip_bfloat16 h; short s; } u;
  u.h = __float2bfloat16(x);   // RNE; compiler can pk-fuse (v_cvt_pk_bf16_f32)
  return u.s;
}

__global__ __launch_bounds__(256) void prep_w_kernel(
    const float* __restrict__ mat1, const float* __restrict__ Alpha,
    const int* __restrict__ use_alpha, short* __restrict__ Aprep) {
  int t = blockIdx.x * 256 + threadIdx.x;   // o = t&255, c = t>>8
  int o = t & 255;
  int c = t >> 8;
  int ua = use_alpha[0];
  const float* src = mat1 + ((size_t)o * C_IN + c) * 8;
  short8 v;
#pragma unroll
  for (int r = 0; r < 8; ++r) {
    float s = ua ? Alpha[r] : 1.0f;
    v[r] = f2bf(src[r] * s);
  }
  // layout: slot (c*256 + o), 8 bf16 (r fastest)
  *(short8*)(Aprep + ((size_t)c * 256 + o) * 8) = v;
}

__global__ __launch_bounds__(256, 2) void gemm_deform_kernel(
    const float* __restrict__ mat0, const short* __restrict__ Aprep,
    const float* __restrict__ mask, float* __restrict__ out) {
  // 16B slots: index = cq*128 + idx, cq = c-plane within round (0..7)
  __shared__ short8 A_lds[2][1024];   // 2 x 16 KiB
  __shared__ short8 B_lds[2][1024];   // 2 x 16 KiB

  int bid = blockIdx.x;
  int wg = (bid & 7) * 64 + (bid >> 3);   // XCD swizzle (512 % 8 == 0, bijective)
  int tile_m = wg & 1;                    // M fastest: pair shares mat0 panel in L2
  int tile_n = wg >> 1;
  int o0 = tile_m * BM;
  int n0 = tile_n * BN;
  int b  = n0 >> 12;
  int p0 = n0 & 4095;

  int t    = threadIdx.x;
  int lane = t & 63;
  int w    = t >> 6;
  int wr   = w >> 1, wc = w & 1;
  int kp   = lane >> 4;
  int li   = lane & 15;

  // B staging ownership: one n-column, 4 c-planes {cr, cr+2, cr+4, cr+6}
  int ns = t & 127;
  int cr = t >> 7;

  const float* m0 = mat0 + (size_t)b * C_IN * HW_ + p0 + ns;

  float mk[8];
#pragma unroll
  for (int r = 0; r < 8; ++r) mk[r] = mask[r * HW_ + p0 + ns];

  f32x4 acc[4][4];
#pragma unroll
  for (int mi = 0; mi < 4; ++mi)
#pragma unroll
    for (int ni = 0; ni < 4; ++ni) acc[mi][ni] = (f32x4){0.f, 0.f, 0.f, 0.f};

  const __attribute__((address_space(1))) uint32_t* gA =
      (const __attribute__((address_space(1))) uint32_t*)Aprep;

  auto stageA = [&](int rd, int buf) {
    int c0 = rd * BKC;
    __attribute__((address_space(3))) uint32_t* lA =
        (__attribute__((address_space(3))) uint32_t*)&A_lds[buf][0];
#pragma unroll
    for (int seg = 0; seg < 4; ++seg) {
      // dest slot = w*256 + seg*64 (+lane by HW) == cq*128 + oo
      int cq = 2 * w + (seg >> 1);
      int oo = (seg & 1) * 64 + lane;
      int gslot = (c0 + cq) * 256 + o0 + oo;
      __builtin_amdgcn_global_load_lds(gA + (size_t)gslot * 4,
                                       lA + (size_t)(w * 256 + seg * 64) * 4,
                                       16, 0, 0);
    }
  };

  auto loadM0 = [&](int rd, float f[4]) {
    const float* p = m0 + (size_t)(rd * BKC + cr) * HW_;
#pragma unroll
    for (int i = 0; i < 4; ++i) f[i] = p[(size_t)(2 * i) * HW_];
  };

  auto writeB = [&](int buf, const float f[4]) {
#pragma unroll
    for (int i = 0; i < 4; ++i) {
      short8 v;
#pragma unroll
      for (int r = 0; r < 8; ++r) v[r] = f2bf(f[i] * mk[r]);
      B_lds[buf][(cr + 2 * i) * 128 + ns] = v;
    }
  };

  auto compute = [&](int buf) {
    short8 af[2][4], bv[2][4];
#pragma unroll
    for (int ks = 0; ks < 2; ++ks) {
      int cq = ks * 4 + kp;
#pragma unroll
      for (int mi = 0; mi < 4; ++mi)
        af[ks][mi] = A_lds[buf][cq * 128 + wr * 64 + mi * 16 + li];
#pragma unroll
      for (int ni = 0; ni < 4; ++ni)
        bv[ks][ni] = B_lds[buf][cq * 128 + wc * 64 + ni * 16 + li];
    }
#pragma unroll
    for (int ks = 0; ks < 2; ++ks)
#pragma unroll
      for (int mi = 0; mi < 4; ++mi)
#pragma unroll
        for (int ni = 0; ni < 4; ++ni)
          acc[mi][ni] = __builtin_amdgcn_mfma_f32_16x16x32_bf16(
              af[ks][mi], bv[ks][ni], acc[mi][ni], 0, 0, 0);
  };

  // ---- prologue: stage round 0 into buf 0 ----
  stageA(0, 0);
  {
    float f[4];
    loadM0(0, f);
    writeB(0, f);
  }
  __syncthreads();

  // ---- main loop: one barrier per round; prefetch issued before compute ----
  for (int rd = 0; rd < NRND; ++rd) {
    int cur = rd & 1;
    float f[4];
    bool pf = (rd + 1 < NRND);
    if (pf) {
      stageA(rd + 1, cur ^ 1);   // global->LDS for next round, in flight across MFMA
      loadM0(rd + 1, f);         // mat0 regs for next round's B transform
    }
    compute(cur);
    if (pf) writeB(cur ^ 1, f);  // transform after MFMA: load latency hidden
    __syncthreads();
  }

  // ---- epilogue: C/D layout col=lane&15, row=(lane>>4)*4+j ----
  size_t obase = (size_t)b * O_DIM * HW_ + p0;
#pragma unroll
  for (int mi = 0; mi < 4; ++mi) {
#pragma unroll
    for (int ni = 0; ni < 4; ++ni) {
      int col = wc * 64 + ni * 16 + li;
#pragma unroll
      for (int j = 0; j < 4; ++j) {
        int row = o0 + wr * 64 + mi * 16 + kp * 4 + j;
        out[obase + (size_t)row * HW_ + col] = acc[mi][ni][j];
      }
    }
  }
}

extern "C" void kernel_launch(void* const* d_in, const int* in_sizes, int n_in,
                              void* d_out, int out_size, void* d_ws, size_t ws_size,
                              hipStream_t stream) {
  const float* mat0      = (const float*)d_in[0];   // [8,256,64,64]
  const float* mat1      = (const float*)d_in[1];   // [256,256,8]
  const float* mask      = (const float*)d_in[2];   // [8,64,64]
  const float* Alpha     = (const float*)d_in[3];   // [8]
  const int*   use_alpha = (const int*)d_in[4];     // [1]
  (void)in_sizes; (void)n_in; (void)out_size; (void)ws_size;

  short* Aprep = (short*)d_ws;                      // 1 MiB scratch
  float* outp  = (float*)d_out;

  prep_w_kernel<<<256, 256, 0, stream>>>(mat1, Alpha, use_alpha, Aprep);
  gemm_deform_kernel<<<512, 256, 0, stream>>>(mat0, Aprep, mask, outp);
}

// Round 3
// 53.275 us; speedup vs baseline: 1.1889x; 1.1625x over previous
//
#include <hip/hip_runtime.h>
#include <hip/hip_bf16.h>
#include <stdint.h>

// out[b,o,p] = sum_{r,c} mat0[b,c,p] * mat1[o,c,r]*Alpha[r] * mask[r,p]
// Single GEMM: M=256 (o), N=32768 (n=b*4096+p), K=2048 (k=c*8+r).
// A[o,k] = mat1[o,c,r]*Alpha[r]  (prepped bf16 in d_ws, layout [c][o][r])
// B[k,n] = mat0[b,c,p]*mask[r,p] generated IN REGISTERS per lane.
// Round 3: zero LDS, zero barriers. A-fragments direct from global (L1/L2),
// B-fragments synthesized per-lane. 2-stage register pipeline (T4-style
// counted vmcnt via compiler), 2 blocks/CU, wave = 64x64 output.

typedef __attribute__((ext_vector_type(8))) short short8;
typedef __attribute__((ext_vector_type(4))) float f32x4;

#define C_IN  256
#define HW_   4096
#define O_DIM 256
#define BM    128
#define BN    128
#define NRND  32    // K rounds of 64 (8 c-planes each)

__device__ __forceinline__ short f2bf(float x) {
  union { __hip_bfloat16 h; short s; } u;
  u.h = __float2bfloat16(x);   // RNE; compiler pk-fuses into v_cvt_pk_bf16_f32
  return u.s;
}

__global__ __launch_bounds__(256) void prep_w_kernel(
    const float* __restrict__ mat1, const float* __restrict__ Alpha,
    const int* __restrict__ use_alpha, short* __restrict__ Aprep) {
  int t = blockIdx.x * 256 + threadIdx.x;   // o = t&255, c = t>>8
  int o = t & 255;
  int c = t >> 8;
  int ua = use_alpha[0];
  const float* src = mat1 + ((size_t)o * C_IN + c) * 8;
  short8 v;
#pragma unroll
  for (int r = 0; r < 8; ++r) {
    float s = ua ? Alpha[r] : 1.0f;
    v[r] = f2bf(src[r] * s);
  }
  // layout: slot (c*256 + o) holds 8 bf16 (r fastest)
  *(short8*)(Aprep + ((size_t)c * 256 + o) * 8) = v;
}

__global__ __launch_bounds__(256, 2) void gemm_deform_kernel(
    const float* __restrict__ mat0, const short* __restrict__ Aprep,
    const float* __restrict__ mask, float* __restrict__ out) {
  int bid = blockIdx.x;
  int wg = (bid & 7) * 64 + (bid >> 3);   // XCD swizzle (512 % 8 == 0, bijective)
  int tile_m = wg & 1;                    // M fastest: co-resident pair shares mat0 cols
  int tile_n = wg >> 1;
  int o0 = tile_m * BM;
  int n0 = tile_n * BN;
  int b  = n0 >> 12;
  int p0 = n0 & 4095;

  int t    = threadIdx.x;
  int lane = t & 63;
  int w    = t >> 6;
  int wr   = w >> 1, wc = w & 1;
  int kp   = lane >> 4;     // k-plane group within fragment
  int li   = lane & 15;     // row (A) / col (B) within fragment

  // lane-resident mask values for this lane's 4 fragment columns
  int colb = p0 + wc * 64 + li;
  float mk[4][8];
#pragma unroll
  for (int ni = 0; ni < 4; ++ni)
#pragma unroll
    for (int r = 0; r < 8; ++r)
      mk[ni][r] = mask[r * HW_ + colb + ni * 16];

  // A fragment source: slot index = c*256 + o  (16B slots)
  const short8* __restrict__ Ap = (const short8*)Aprep;
  int abase0 = kp * 256 + o0 + wr * 64 + li;   // + (rd*8+ks*4)*256 + mi*16

  // mat0 source for this lane: row (c) part kp, col part colb
  const float* __restrict__ m0 = mat0 + ((size_t)b * C_IN + kp) * HW_ + colb;

  f32x4 acc[4][4];
#pragma unroll
  for (int mi = 0; mi < 4; ++mi)
#pragma unroll
    for (int ni = 0; ni < 4; ++ni) acc[mi][ni] = (f32x4){0.f, 0.f, 0.f, 0.f};

  short8 afA[2][4], afB[2][4];
  float  m0A[2][4], m0B[2][4];

  auto LOAD = [&](short8 (&af)[2][4], float (&m0v)[2][4], int rd) {
    int ab = rd * 8 * 256 + abase0;
#pragma unroll
    for (int ks = 0; ks < 2; ++ks)
#pragma unroll
      for (int mi = 0; mi < 4; ++mi)
        af[ks][mi] = Ap[ab + ks * 4 * 256 + mi * 16];
    const float* mp = m0 + (size_t)(rd * 8) * HW_;
#pragma unroll
    for (int ks = 0; ks < 2; ++ks)
#pragma unroll
      for (int ni = 0; ni < 4; ++ni)
        m0v[ks][ni] = mp[(size_t)(ks * 4) * HW_ + ni * 16];
  };

  auto COMP = [&](const short8 (&af)[2][4], const float (&m0v)[2][4]) {
#pragma unroll
    for (int ks = 0; ks < 2; ++ks) {
      short8 bv[4];
#pragma unroll
      for (int ni = 0; ni < 4; ++ni)
#pragma unroll
        for (int r = 0; r < 8; ++r)
          bv[ni][r] = f2bf(m0v[ks][ni] * mk[ni][r]);
#pragma unroll
      for (int mi = 0; mi < 4; ++mi)
#pragma unroll
        for (int ni = 0; ni < 4; ++ni)
          acc[mi][ni] = __builtin_amdgcn_mfma_f32_16x16x32_bf16(
              af[ks][mi], bv[ni], acc[mi][ni], 0, 0, 0);
    }
  };

  // 2-stage register pipeline: LOAD(next) always a full COMP ahead of use.
  LOAD(afA, m0A, 0);
#pragma unroll 1
  for (int rd = 0; rd < NRND; rd += 2) {
    LOAD(afB, m0B, rd + 1);
    COMP(afA, m0A);
    if (rd + 2 < NRND) LOAD(afA, m0A, rd + 2);
    COMP(afB, m0B);
  }

  // epilogue: C/D layout col=lane&15, row=(lane>>4)*4+j
  size_t obase = (size_t)b * O_DIM * HW_ + p0;
#pragma unroll
  for (int mi = 0; mi < 4; ++mi) {
#pragma unroll
    for (int ni = 0; ni < 4; ++ni) {
      int col = wc * 64 + ni * 16 + li;
#pragma unroll
      for (int j = 0; j < 4; ++j) {
        int row = o0 + wr * 64 + mi * 16 + kp * 4 + j;
        out[obase + (size_t)row * HW_ + col] = acc[mi][ni][j];
      }
    }
  }
}

extern "C" void kernel_launch(void* const* d_in, const int* in_sizes, int n_in,
                              void* d_out, int out_size, void* d_ws, size_t ws_size,
                              hipStream_t stream) {
  const float* mat0      = (const float*)d_in[0];   // [8,256,64,64]
  const float* mat1      = (const float*)d_in[1];   // [256,256,8]
  const float* mask      = (const float*)d_in[2];   // [8,64,64]
  const float* Alpha     = (const float*)d_in[3];   // [8]
  const int*   use_alpha = (const int*)d_in[4];     // [1]
  (void)in_sizes; (void)n_in; (void)out_size; (void)ws_size;

  short* Aprep = (short*)d_ws;                      // 1 MiB scratch
  float* outp  = (float*)d_out;

  prep_w_kernel<<<256, 256, 0, stream>>>(mat1, Alpha, use_alpha, Aprep);
  gemm_deform_kernel<<<512, 256, 0, stream>>>(mat0, Aprep, mask, outp);
}